// Round 1
// baseline (359.869 us; speedup 1.0000x reference)
//
#include <hip/hip_runtime.h>

#define N_NODES 50000
#define N_EDGES 800000
#define D 64
#define NBUCKETS 196          // dst>>8, 0..195
#define BCAP 8192             // fixed bucket capacity (Poisson(4082), 5sigma<4400)
#define SBLOCKS 256           // scatter blocks
#define CHUNK (N_EDGES / SBLOCKS)   // 3125
#define CASTBLOCKS 3125       // N*D/4 ushort4 items / 256 threads

// bf16 helpers (RNE), bit-level.
__device__ __forceinline__ unsigned short f2bf(float f) {
    unsigned u = __float_as_uint(f);
    return (unsigned short)((u + 0x7fffu + ((u >> 16) & 1u)) >> 16);
}
__device__ __forceinline__ float bflo(unsigned u) {
    return __uint_as_float(u << 16);
}
__device__ __forceinline__ float bfhi(unsigned u) {
    return __uint_as_float(u & 0xffff0000u);
}

// ---------- Scatter into fixed-capacity buckets + fused x->bf16 cast --------
// Pass 1 loads src+dst once, packs into LDS; pass 2 scatters from LDS
// (removes the 6.4 MB global re-read of the previous version).
__global__ void __launch_bounds__(256) scatter_cast_kernel(
    const int* __restrict__ src, const int* __restrict__ dst,
    const float* __restrict__ X,
    int* __restrict__ cursorPad, int* __restrict__ staged,
    unsigned short* __restrict__ Xbf) {
    int t = threadIdx.x;
    if (blockIdx.x >= SBLOCKS) {
        int i = (blockIdx.x - SBLOCKS) * 256 + t;   // over N*D/4
        float4 v = ((const float4*)X)[i];
        ushort4 r;
        r.x = f2bf(v.x); r.y = f2bf(v.y); r.z = f2bf(v.z); r.w = f2bf(v.w);
        ((ushort4*)Xbf)[i] = r;
        return;
    }
    __shared__ int hist[256];
    __shared__ int curs[256];
    __shared__ int pk[CHUNK];              // packed (src<<8)|(dst&255)
    __shared__ unsigned char bk[CHUNK];    // bucket id (dst>>8)
    hist[t] = 0;
    __syncthreads();
    int lo = blockIdx.x * CHUNK;
    for (int i = t; i < CHUNK; i += 256) {
        int d = dst[lo + i];
        int s = src[lo + i];
        pk[i] = (s << 8) | (d & 255);
        bk[i] = (unsigned char)(d >> 8);
        atomicAdd(&hist[d >> 8], 1);
    }
    __syncthreads();
    if (hist[t] > 0)
        curs[t] = t * BCAP + atomicAdd(&cursorPad[t * 16], hist[t]);
    __syncthreads();
    for (int i = t; i < CHUNK; i += 256) {
        int b = bk[i];
        int pos = atomicAdd(&curs[b], 1);
        staged[pos] = pk[i];
    }
}

// ---------- Per-bucket CSR build (padded regions; LDS scan + cursors) -------
__global__ void __launch_bounds__(256) csr_build_kernel(
    const int* __restrict__ cursorPad, const int* __restrict__ staged,
    int* __restrict__ csr, int* __restrict__ startA, int* __restrict__ endA) {
    __shared__ int deg[256];
    __shared__ int sc[256];
    __shared__ int curs[256];
    int k = blockIdx.x;
    int t = threadIdx.x;
    int base = k * BCAP;
    int cnt  = cursorPad[k * 16];
    deg[t] = 0;
    __syncthreads();
    for (int i = t; i < cnt; i += 256)
        atomicAdd(&deg[staged[base + i] & 255], 1);
    __syncthreads();
    int v = deg[t];
    sc[t] = v;
    __syncthreads();
#pragma unroll
    for (int d = 1; d < 256; d <<= 1) {
        int u = (t >= d) ? sc[t - d] : 0;
        __syncthreads();
        sc[t] += u;
        __syncthreads();
    }
    int start = sc[t] - v;
    int node = k * 256 + t;
    if (node < N_NODES) {
        startA[node] = base + start;
        endA[node]   = base + start + v;
    }
    curs[t] = start;
    __syncthreads();
    for (int i = t; i < cnt; i += 256) {
        int e = staged[base + i];
        int pos = atomicAdd(&curs[e & 255], 1);
        csr[base + pos] = e >> 8;
    }
}

// ---------- Fused gather + register-blocked dual GEMM -----------------------
// Per block: 64 nodes. Phase A: stage W (fp32) + X (fp32 or bf16) into LDS,
// and gather neighbor-sum rows (bf16 source Gsrc) directly into sAT.
// Phase B: the verified dual-GEMM body. One __syncthreads between phases.
// Gather body is the verified R8 structure (16-lane row groups, shfl index
// distribution, batch-16 main + batch-4 tail, cross-sub xor reduce).
template<int RELU, int WOUT, int WBF, int XBF>
__global__ void __launch_bounds__(256) fused_layer(
    const float* __restrict__ Xf, const unsigned short* __restrict__ Xb,
    const unsigned short* __restrict__ Gsrc,
    const int* __restrict__ startA, const int* __restrict__ endA,
    const int* __restrict__ csr,
    const float* __restrict__ Wr, const float* __restrict__ Wn,
    const float* __restrict__ bias, float* __restrict__ out,
    unsigned short* __restrict__ outBf) {
    __shared__ float sXT[D][D];
    __shared__ float sAT[D][D];
    __shared__ float sWr[D][D];
    __shared__ float sWn[D][D];

    int tid = threadIdx.x;
    int node0 = blockIdx.x * 64;

    // ---- stage weights
#pragma unroll
    for (int i = 0; i < 4; i++) {
        int idx = tid + 256 * i;
        ((float4*)sWr)[idx] = ((const float4*)Wr)[idx];
        ((float4*)sWn)[idx] = ((const float4*)Wn)[idx];
    }
    // ---- stage X (root operand), transposed into sXT[k][node]
    int nd = tid & 63;
    int gn = min(node0 + nd, N_NODES - 1);
    if (XBF) {
#pragma unroll
        for (int pass = 0; pass < 2; pass++) {
            int kg = (tid >> 6) + pass * 4;       // 0..7
            int k0 = kg * 8;
            uint4 ux = *(const uint4*)(Xb + (size_t)gn * D + k0);
            sXT[k0 + 0][nd] = bflo(ux.x); sXT[k0 + 1][nd] = bfhi(ux.x);
            sXT[k0 + 2][nd] = bflo(ux.y); sXT[k0 + 3][nd] = bfhi(ux.y);
            sXT[k0 + 4][nd] = bflo(ux.z); sXT[k0 + 5][nd] = bfhi(ux.z);
            sXT[k0 + 6][nd] = bflo(ux.w); sXT[k0 + 7][nd] = bfhi(ux.w);
        }
    } else {
        const float4* X4 = (const float4*)Xf;
#pragma unroll
        for (int pass = 0; pass < 4; pass++) {
            int kq = (tid >> 6) + pass * 4;
            float4 v = X4[gn * 16 + kq];
            sXT[kq * 4 + 0][nd] = v.x; sXT[kq * 4 + 1][nd] = v.y;
            sXT[kq * 4 + 2][nd] = v.z; sXT[kq * 4 + 3][nd] = v.w;
        }
    }

    // ---- gather: wave w handles nodes node0 + w*16 .. +15, writes sAT[k][c]
    int wave = tid >> 6, lane = tid & 63;
    int sub = lane >> 4, fq = lane & 15;
    for (int n = 0; n < 16; ++n) {
        int c = wave * 16 + n;
        int node = min(node0 + c, N_NODES - 1);   // clamp pad nodes (>=50000)
        int j0 = startA[node], je = endA[node];
        float a0 = 0.f, a1 = 0.f, a2 = 0.f, a3 = 0.f;
        for (int jb = j0; jb < je; jb += 64) {          // je wave-uniform
            int idx = jb + lane;
            int p = csr[idx < je ? idx : (je - 1)];     // coalesced index batch
            int m = min(64, je - jb);                   // wave-uniform
            int b = 0;
            for (; b + 16 <= m; b += 16) {
                int i0 = __shfl(p, b + sub, 64);
                int i1 = __shfl(p, b + 4 + sub, 64);
                int i2 = __shfl(p, b + 8 + sub, 64);
                int i3 = __shfl(p, b + 12 + sub, 64);
                uint2 u0 = *(const uint2*)(Gsrc + i0 * D + fq * 4);
                uint2 u1 = *(const uint2*)(Gsrc + i1 * D + fq * 4);
                uint2 u2 = *(const uint2*)(Gsrc + i2 * D + fq * 4);
                uint2 u3 = *(const uint2*)(Gsrc + i3 * D + fq * 4);
                a0 += bflo(u0.x) + bflo(u1.x) + bflo(u2.x) + bflo(u3.x);
                a1 += bfhi(u0.x) + bfhi(u1.x) + bfhi(u2.x) + bfhi(u3.x);
                a2 += bflo(u0.y) + bflo(u1.y) + bflo(u2.y) + bflo(u3.y);
                a3 += bfhi(u0.y) + bfhi(u1.y) + bfhi(u2.y) + bfhi(u3.y);
            }
            for (; b < m; b += 4) {                     // uniform condition
                int sidx = b + sub;
                int scl = sidx < m ? sidx : (m - 1);    // active source lane
                int i0 = __shfl(p, scl, 64);            // executed by ALL lanes
                if (sidx < m) {                         // divergence only here
                    uint2 u = *(const uint2*)(Gsrc + i0 * D + fq * 4);
                    a0 += bflo(u.x); a1 += bfhi(u.x);
                    a2 += bflo(u.y); a3 += bfhi(u.y);
                }
            }
        }
#pragma unroll
        for (int mk = 16; mk <= 32; mk <<= 1) {
            a0 += __shfl_xor(a0, mk, 64);
            a1 += __shfl_xor(a1, mk, 64);
            a2 += __shfl_xor(a2, mk, 64);
            a3 += __shfl_xor(a3, mk, 64);
        }
        if (sub == 0) {
            sAT[fq * 4 + 0][c] = a0;
            sAT[fq * 4 + 1][c] = a1;
            sAT[fq * 4 + 2][c] = a2;
            sAT[fq * 4 + 3][c] = a3;
        }
    }
    __syncthreads();

    // ---- dual GEMM (verified body, unchanged)
    int nq = tid >> 4;
    int cq = tid & 15;
    float4 b4 = ((const float4*)bias)[cq];
    float acc[4][4];
#pragma unroll
    for (int i = 0; i < 4; i++) {
        acc[i][0] = b4.x; acc[i][1] = b4.y; acc[i][2] = b4.z; acc[i][3] = b4.w;
    }

#pragma unroll 16
    for (int k = 0; k < D; k++) {
        float4 xv = *(const float4*)&sXT[k][nq * 4];
        float4 av = *(const float4*)&sAT[k][nq * 4];
        float4 wr = *(const float4*)&sWr[k][cq * 4];
        float4 wn = *(const float4*)&sWn[k][cq * 4];
        float xs[4] = {xv.x, xv.y, xv.z, xv.w};
        float as[4] = {av.x, av.y, av.z, av.w};
        float rs[4] = {wr.x, wr.y, wr.z, wr.w};
        float ns[4] = {wn.x, wn.y, wn.z, wn.w};
#pragma unroll
        for (int i = 0; i < 4; i++)
#pragma unroll
            for (int jj = 0; jj < 4; jj++) {
                acc[i][jj] = fmaf(xs[i], rs[jj], acc[i][jj]);
                acc[i][jj] = fmaf(as[i], ns[jj], acc[i][jj]);
            }
    }

    float4* out4 = (float4*)out;
#pragma unroll
    for (int i = 0; i < 4; i++) {
        int node = node0 + nq * 4 + i;
        if (node < N_NODES) {
            float4 r;
            r.x = acc[i][0]; r.y = acc[i][1]; r.z = acc[i][2]; r.w = acc[i][3];
            if (RELU) {
                r.x = fmaxf(r.x, 0.f); r.y = fmaxf(r.y, 0.f);
                r.z = fmaxf(r.z, 0.f); r.w = fmaxf(r.w, 0.f);
            }
            if (WOUT) out4[node * 16 + cq] = r;
            if (WBF) {
                ushort4 rb;
                rb.x = f2bf(r.x); rb.y = f2bf(r.y);
                rb.z = f2bf(r.z); rb.w = f2bf(r.w);
                *(ushort4*)(outBf + (size_t)node * D + cq * 4) = rb;
            }
        }
    }
}

// ---------- launch ----------------------------------------------------------
extern "C" void kernel_launch(void* const* d_in, const int* in_sizes, int n_in,
                              void* d_out, int out_size, void* d_ws, size_t ws_size,
                              hipStream_t stream) {
    const float* x   = (const float*)d_in[0];
    const int*   edg = (const int*)d_in[1];
    const float* W1r = (const float*)d_in[2];
    const float* W1n = (const float*)d_in[3];
    const float* b1  = (const float*)d_in[4];
    const float* W2r = (const float*)d_in[5];
    const float* W2n = (const float*)d_in[6];
    const float* b2  = (const float*)d_in[7];
    float* out = (float*)d_out;

    const int* src = edg;
    const int* dst = edg + N_EDGES;

    // ws (256 MiB available) — generous non-overlapping padded layout.
    int* W              = (int*)d_ws;
    int* cursorPad      = W;                         // 196*16 ints
    int* staged         = W + 4096;                  // NBUCKETS*BCAP
    int* csr            = staged + NBUCKETS * BCAP;  // NBUCKETS*BCAP
    int* startA         = csr + NBUCKETS * BCAP;
    int* endA           = startA + N_NODES;
    unsigned short* xbf = (unsigned short*)(endA + N_NODES);   // N*D bf16
    unsigned short* hbf = xbf + (size_t)N_NODES * D;           // N*D bf16

    hipMemsetAsync(cursorPad, 0, 196 * 16 * sizeof(int), stream);
    scatter_cast_kernel<<<SBLOCKS + CASTBLOCKS, 256, 0, stream>>>(
        src, dst, x, cursorPad, staged, xbf);
    csr_build_kernel<<<NBUCKETS, 256, 0, stream>>>(cursorPad, staged, csr,
                                                   startA, endA);

    const int MB = (N_NODES + 63) / 64;  // 782

    // Layer 1: X from fp32 x, gather from xbf; write ONLY hbf (no fp32 h).
    fused_layer<1, 0, 1, 0><<<MB, 256, 0, stream>>>(
        x, (const unsigned short*)0, xbf, startA, endA, csr,
        W1r, W1n, b1, out, hbf);
    // Layer 2: X from bf16 hbf, gather from hbf; write fp32 out.
    fused_layer<0, 1, 0, 1><<<MB, 256, 0, stream>>>(
        (const float*)0, hbf, hbf, startA, endA, csr,
        W2r, W2n, b2, out, (unsigned short*)0);
}

// Round 2
// 174.858 us; speedup vs baseline: 2.0581x; 2.0581x over previous
//
#include <hip/hip_runtime.h>

#define N_NODES 50000
#define N_EDGES 800000
#define D 64
#define NBUCKETS 196          // dst>>8, 0..195
#define BCAP 8192             // fixed bucket capacity (Poisson(4082), 5sigma<4400)
#define SBLOCKS 256           // scatter blocks
#define CHUNK (N_EDGES / SBLOCKS)   // 3125
#define MB ((N_NODES + 63) / 64)    // 782 gemm blocks

// bf16 helpers (RNE), bit-level.
__device__ __forceinline__ unsigned short f2bf(float f) {
    unsigned u = __float_as_uint(f);
    return (unsigned short)((u + 0x7fffu + ((u >> 16) & 1u)) >> 16);
}
__device__ __forceinline__ float bflo(unsigned u) {
    return __uint_as_float(u << 16);
}
__device__ __forceinline__ float bfhi(unsigned u) {
    return __uint_as_float(u & 0xffff0000u);
}

// ---------- scatter body (verified R1 form; LDS passed in) ------------------
__device__ __forceinline__ void scatter_body(
    const int* __restrict__ src, const int* __restrict__ dst,
    int* __restrict__ cursorPad, int* __restrict__ staged,
    char* smem, int bid, int t) {
    int* hist = (int*)smem;                       // 256 ints
    int* curs = (int*)(smem + 1024);              // 256 ints
    int* pk   = (int*)(smem + 2048);              // CHUNK ints
    unsigned char* bk = (unsigned char*)(smem + 2048 + CHUNK * 4);
    hist[t] = 0;
    __syncthreads();
    int lo = bid * CHUNK;
    for (int i = t; i < CHUNK; i += 256) {
        int d = dst[lo + i];
        int s = src[lo + i];
        pk[i] = (s << 8) | (d & 255);
        bk[i] = (unsigned char)(d >> 8);
        atomicAdd(&hist[d >> 8], 1);
    }
    __syncthreads();
    if (hist[t] > 0)
        curs[t] = t * BCAP + atomicAdd(&cursorPad[t * 16], hist[t]);
    __syncthreads();
    for (int i = t; i < CHUNK; i += 256) {
        int b = bk[i];
        int pos = atomicAdd(&curs[b], 1);
        staged[pos] = pk[i];
    }
}

// ---------- dual-output GEMM body: R = X@Wr (fp32), Nn = X@Wn (bf16) --------
// Derived from the verified dual_gemm body; same staging/layouts, but two
// independent accumulators and no bias (bias folded into gather epilogue).
template<int XBF>
__device__ __forceinline__ void gemm_body(
    const float* __restrict__ Xf, const unsigned short* __restrict__ Xb,
    const float* __restrict__ Wr, const float* __restrict__ Wn,
    float* __restrict__ outR, unsigned short* __restrict__ outN,
    int node0, int tid, char* smem) {
    float (*sXT)[D] = (float(*)[D])smem;             // 16 KB
    float (*sWr)[D] = (float(*)[D])(smem + 16384);   // 16 KB
    float (*sWn)[D] = (float(*)[D])(smem + 32768);   // 16 KB

#pragma unroll
    for (int i = 0; i < 4; i++) {
        int idx = tid + 256 * i;
        ((float4*)sWr)[idx] = ((const float4*)Wr)[idx];
        ((float4*)sWn)[idx] = ((const float4*)Wn)[idx];
    }
    int nd = tid & 63;
    int gn = min(node0 + nd, N_NODES - 1);
    if (XBF) {
#pragma unroll
        for (int pass = 0; pass < 2; pass++) {
            int kg = (tid >> 6) + pass * 4;       // 0..7
            int k0 = kg * 8;
            uint4 ux = *(const uint4*)(Xb + (size_t)gn * D + k0);
            sXT[k0 + 0][nd] = bflo(ux.x); sXT[k0 + 1][nd] = bfhi(ux.x);
            sXT[k0 + 2][nd] = bflo(ux.y); sXT[k0 + 3][nd] = bfhi(ux.y);
            sXT[k0 + 4][nd] = bflo(ux.z); sXT[k0 + 5][nd] = bfhi(ux.z);
            sXT[k0 + 6][nd] = bflo(ux.w); sXT[k0 + 7][nd] = bfhi(ux.w);
        }
    } else {
        const float4* X4 = (const float4*)Xf;
#pragma unroll
        for (int pass = 0; pass < 4; pass++) {
            int kq = (tid >> 6) + pass * 4;
            float4 v = X4[gn * 16 + kq];
            sXT[kq * 4 + 0][nd] = v.x; sXT[kq * 4 + 1][nd] = v.y;
            sXT[kq * 4 + 2][nd] = v.z; sXT[kq * 4 + 3][nd] = v.w;
        }
    }
    __syncthreads();

    int nq = tid >> 4;
    int cq = tid & 15;
    float accR[4][4];
    float accN[4][4];
#pragma unroll
    for (int i = 0; i < 4; i++)
#pragma unroll
        for (int jj = 0; jj < 4; jj++) { accR[i][jj] = 0.f; accN[i][jj] = 0.f; }

#pragma unroll 16
    for (int k = 0; k < D; k++) {
        float4 xv = *(const float4*)&sXT[k][nq * 4];
        float4 wr = *(const float4*)&sWr[k][cq * 4];
        float4 wn = *(const float4*)&sWn[k][cq * 4];
        float xs[4] = {xv.x, xv.y, xv.z, xv.w};
        float rs[4] = {wr.x, wr.y, wr.z, wr.w};
        float ns[4] = {wn.x, wn.y, wn.z, wn.w};
#pragma unroll
        for (int i = 0; i < 4; i++)
#pragma unroll
            for (int jj = 0; jj < 4; jj++) {
                accR[i][jj] = fmaf(xs[i], rs[jj], accR[i][jj]);
                accN[i][jj] = fmaf(xs[i], ns[jj], accN[i][jj]);
            }
    }

    float4* outR4 = (float4*)outR;
#pragma unroll
    for (int i = 0; i < 4; i++) {
        int node = node0 + nq * 4 + i;
        if (node < N_NODES) {
            float4 r;
            r.x = accR[i][0]; r.y = accR[i][1];
            r.z = accR[i][2]; r.w = accR[i][3];
            outR4[node * 16 + cq] = r;
            ushort4 rb;
            rb.x = f2bf(accN[i][0]); rb.y = f2bf(accN[i][1]);
            rb.z = f2bf(accN[i][2]); rb.w = f2bf(accN[i][3]);
            *(ushort4*)(outN + (size_t)node * D + cq * 4) = rb;
        }
    }
}

// ---------- merged scatter + layer-1 GEMM (block-specialized) ---------------
__global__ void __launch_bounds__(256) scatter_gemm1(
    const int* __restrict__ src, const int* __restrict__ dst,
    int* __restrict__ cursorPad, int* __restrict__ staged,
    const float* __restrict__ X,
    const float* __restrict__ Wr, const float* __restrict__ Wn,
    float* __restrict__ xr, unsigned short* __restrict__ xn) {
    __shared__ char smem[49152];
    if (blockIdx.x < SBLOCKS) {
        scatter_body(src, dst, cursorPad, staged, smem, blockIdx.x, threadIdx.x);
    } else {
        gemm_body<0>(X, (const unsigned short*)0, Wr, Wn, xr, xn,
                     (blockIdx.x - SBLOCKS) * 64, threadIdx.x, smem);
    }
}

// ---------- standalone layer-2 GEMM (bf16 input) ----------------------------
__global__ void __launch_bounds__(256) gemm2(
    const unsigned short* __restrict__ Xb,
    const float* __restrict__ Wr, const float* __restrict__ Wn,
    float* __restrict__ hr, unsigned short* __restrict__ hn) {
    __shared__ char smem[49152];
    gemm_body<1>((const float*)0, Xb, Wr, Wn, hr, hn,
                 blockIdx.x * 64, threadIdx.x, smem);
}

// ---------- Per-bucket CSR build (verified; unchanged) ----------------------
__global__ void __launch_bounds__(256) csr_build_kernel(
    const int* __restrict__ cursorPad, const int* __restrict__ staged,
    int* __restrict__ csr, int* __restrict__ startA, int* __restrict__ endA) {
    __shared__ int deg[256];
    __shared__ int sc[256];
    __shared__ int curs[256];
    int k = blockIdx.x;
    int t = threadIdx.x;
    int base = k * BCAP;
    int cnt  = cursorPad[k * 16];
    deg[t] = 0;
    __syncthreads();
    for (int i = t; i < cnt; i += 256)
        atomicAdd(&deg[staged[base + i] & 255], 1);
    __syncthreads();
    int v = deg[t];
    sc[t] = v;
    __syncthreads();
#pragma unroll
    for (int d = 1; d < 256; d <<= 1) {
        int u = (t >= d) ? sc[t - d] : 0;
        __syncthreads();
        sc[t] += u;
        __syncthreads();
    }
    int start = sc[t] - v;
    int node = k * 256 + t;
    if (node < N_NODES) {
        startA[node] = base + start;
        endA[node]   = base + start + v;
    }
    curs[t] = start;
    __syncthreads();
    for (int i = t; i < cnt; i += 256) {
        int e = staged[base + i];
        int pos = atomicAdd(&curs[e & 255], 1);
        csr[base + pos] = e >> 8;
    }
}

// ---------- Gather (verified R8 body) + fused epilogue ----------------------
// agg = sum of bf16 rows Gsrc[csr[...]]; out = act(Root + agg + bias).
// RELU: apply relu. OUTBF: write bf16 (layer1 h) else fp32 (final out).
template<int RELU, int OUTBF>
__global__ void __launch_bounds__(256) gather_fused(
    const unsigned short* __restrict__ Gsrc, const float* __restrict__ Root,
    const float* __restrict__ bias,
    const int* __restrict__ startA, const int* __restrict__ endA,
    const int* __restrict__ csr,
    float* __restrict__ outF, unsigned short* __restrict__ outB) {
    int tid = threadIdx.x;
    int wave = tid >> 6, lane = tid & 63;
    int node = blockIdx.x * 4 + wave;
    int sub = lane >> 4, fq = lane & 15;
    int j0 = startA[node], je = endA[node];
    float a0 = 0.f, a1 = 0.f, a2 = 0.f, a3 = 0.f;
    for (int jb = j0; jb < je; jb += 64) {          // je wave-uniform
        int idx = jb + lane;
        int p = csr[idx < je ? idx : (je - 1)];     // coalesced index batch
        int m = min(64, je - jb);                   // wave-uniform
        int b = 0;
        for (; b + 16 <= m; b += 16) {
            int i0 = __shfl(p, b + sub, 64);
            int i1 = __shfl(p, b + 4 + sub, 64);
            int i2 = __shfl(p, b + 8 + sub, 64);
            int i3 = __shfl(p, b + 12 + sub, 64);
            uint2 u0 = *(const uint2*)(Gsrc + i0 * D + fq * 4);
            uint2 u1 = *(const uint2*)(Gsrc + i1 * D + fq * 4);
            uint2 u2 = *(const uint2*)(Gsrc + i2 * D + fq * 4);
            uint2 u3 = *(const uint2*)(Gsrc + i3 * D + fq * 4);
            a0 += bflo(u0.x) + bflo(u1.x) + bflo(u2.x) + bflo(u3.x);
            a1 += bfhi(u0.x) + bfhi(u1.x) + bfhi(u2.x) + bfhi(u3.x);
            a2 += bflo(u0.y) + bflo(u1.y) + bflo(u2.y) + bflo(u3.y);
            a3 += bfhi(u0.y) + bfhi(u1.y) + bfhi(u2.y) + bfhi(u3.y);
        }
        for (; b < m; b += 4) {                     // uniform condition
            int sidx = b + sub;
            int scl = sidx < m ? sidx : (m - 1);    // active source lane
            int i0 = __shfl(p, scl, 64);            // executed by ALL lanes
            if (sidx < m) {                         // divergence only here
                uint2 u = *(const uint2*)(Gsrc + i0 * D + fq * 4);
                a0 += bflo(u.x); a1 += bfhi(u.x);
                a2 += bflo(u.y); a3 += bfhi(u.y);
            }
        }
    }
#pragma unroll
    for (int mk = 16; mk <= 32; mk <<= 1) {
        a0 += __shfl_xor(a0, mk, 64);
        a1 += __shfl_xor(a1, mk, 64);
        a2 += __shfl_xor(a2, mk, 64);
        a3 += __shfl_xor(a3, mk, 64);
    }
    if (sub == 0) {
        float4 xr = *(const float4*)(Root + (size_t)node * D + fq * 4);
        float4 b4 = ((const float4*)bias)[fq];
        float r0 = a0 + xr.x + b4.x;
        float r1 = a1 + xr.y + b4.y;
        float r2 = a2 + xr.z + b4.z;
        float r3 = a3 + xr.w + b4.w;
        if (RELU) {
            r0 = fmaxf(r0, 0.f); r1 = fmaxf(r1, 0.f);
            r2 = fmaxf(r2, 0.f); r3 = fmaxf(r3, 0.f);
        }
        if (OUTBF) {
            ushort4 rb;
            rb.x = f2bf(r0); rb.y = f2bf(r1); rb.z = f2bf(r2); rb.w = f2bf(r3);
            *(ushort4*)(outB + (size_t)node * D + fq * 4) = rb;
        } else {
            float4 r; r.x = r0; r.y = r1; r.z = r2; r.w = r3;
            *(float4*)(outF + (size_t)node * D + fq * 4) = r;
        }
    }
}

// ---------- launch ----------------------------------------------------------
extern "C" void kernel_launch(void* const* d_in, const int* in_sizes, int n_in,
                              void* d_out, int out_size, void* d_ws, size_t ws_size,
                              hipStream_t stream) {
    const float* x   = (const float*)d_in[0];
    const int*   edg = (const int*)d_in[1];
    const float* W1r = (const float*)d_in[2];
    const float* W1n = (const float*)d_in[3];
    const float* b1  = (const float*)d_in[4];
    const float* W2r = (const float*)d_in[5];
    const float* W2n = (const float*)d_in[6];
    const float* b2  = (const float*)d_in[7];
    float* out = (float*)d_out;

    const int* src = edg;
    const int* dst = edg + N_EDGES;

    // ws (256 MiB) — non-overlapping padded layout.
    int* W              = (int*)d_ws;
    int* cursorPad      = W;                         // 196*16 ints
    int* staged         = W + 4096;                  // NBUCKETS*BCAP
    int* csr            = staged + NBUCKETS * BCAP;  // NBUCKETS*BCAP
    int* startA         = csr + NBUCKETS * BCAP;
    int* endA           = startA + N_NODES;
    float* xr           = (float*)(endA + N_NODES);  // fp32 [N][64] root L1
    unsigned short* xn  = (unsigned short*)(xr + (size_t)N_NODES * D); // bf16 x@W1n
    unsigned short* hbf = xn + (size_t)N_NODES * D;  // bf16 h
    float* hr           = (float*)(hbf + (size_t)N_NODES * D);        // fp32 h@W2r
    unsigned short* hn  = (unsigned short*)(hr + (size_t)N_NODES * D); // bf16 h@W2n

    hipMemsetAsync(cursorPad, 0, 196 * 16 * sizeof(int), stream);

    // [scatter || layer-1 dual GEMM]  (xr = x@W1r fp32, xn = x@W1n bf16)
    scatter_gemm1<<<SBLOCKS + MB, 256, 0, stream>>>(
        src, dst, cursorPad, staged, x, W1r, W1n, xr, xn);

    csr_build_kernel<<<NBUCKETS, 256, 0, stream>>>(cursorPad, staged, csr,
                                                   startA, endA);

    const int GB = N_NODES / 4;          // 12500

    // h = relu(xr + segsum(xn[src]) + b1), written bf16.
    gather_fused<1, 1><<<GB, 256, 0, stream>>>(
        xn, xr, b1, startA, endA, csr, (float*)0, hbf);

    // layer-2 dual GEMM: hr = h@W2r fp32, hn = h@W2n bf16.
    gemm2<<<MB, 256, 0, stream>>>(hbf, W2r, W2n, hr, hn);

    // out = hr + segsum(hn[src]) + b2, written fp32.
    gather_fused<0, 0><<<GB, 256, 0, stream>>>(
        hn, hr, b2, startA, endA, csr, out, (unsigned short*)0);
}

// Round 3
// 173.821 us; speedup vs baseline: 2.0703x; 1.0060x over previous
//
#include <hip/hip_runtime.h>

#define N_NODES 50000
#define N_EDGES 800000
#define D 64
#define NBUCKETS 196          // dst>>8, 0..195
#define BCAP 8192             // fixed bucket capacity (Poisson(4082), 5sigma<4400)
#define SBLOCKS 256           // scatter blocks
#define CHUNK (N_EDGES / SBLOCKS)   // 3125
#define MB ((N_NODES + 63) / 64)    // 782 gemm blocks

// bf16 helpers (RNE), bit-level.
__device__ __forceinline__ unsigned short f2bf(float f) {
    unsigned u = __float_as_uint(f);
    return (unsigned short)((u + 0x7fffu + ((u >> 16) & 1u)) >> 16);
}
__device__ __forceinline__ float bflo(unsigned u) {
    return __uint_as_float(u << 16);
}
__device__ __forceinline__ float bfhi(unsigned u) {
    return __uint_as_float(u & 0xffff0000u);
}

// ---------- scatter body (verified R1 form; LDS passed in) ------------------
__device__ __forceinline__ void scatter_body(
    const int* __restrict__ src, const int* __restrict__ dst,
    int* __restrict__ cursorPad, int* __restrict__ staged,
    char* smem, int bid, int t) {
    int* hist = (int*)smem;                       // 256 ints
    int* curs = (int*)(smem + 1024);              // 256 ints
    int* pk   = (int*)(smem + 2048);              // CHUNK ints
    unsigned char* bk = (unsigned char*)(smem + 2048 + CHUNK * 4);
    hist[t] = 0;
    __syncthreads();
    int lo = bid * CHUNK;
    for (int i = t; i < CHUNK; i += 256) {
        int d = dst[lo + i];
        int s = src[lo + i];
        pk[i] = (s << 8) | (d & 255);
        bk[i] = (unsigned char)(d >> 8);
        atomicAdd(&hist[d >> 8], 1);
    }
    __syncthreads();
    if (hist[t] > 0)
        curs[t] = t * BCAP + atomicAdd(&cursorPad[t * 16], hist[t]);
    __syncthreads();
    for (int i = t; i < CHUNK; i += 256) {
        int b = bk[i];
        int pos = atomicAdd(&curs[b], 1);
        staged[pos] = pk[i];
    }
}

// ---------- dual-output GEMM body: R = X@Wr (fp32), Nn = X@Wn (bf16) --------
template<int XBF>
__device__ __forceinline__ void gemm_body(
    const float* __restrict__ Xf, const unsigned short* __restrict__ Xb,
    const float* __restrict__ Wr, const float* __restrict__ Wn,
    float* __restrict__ outR, unsigned short* __restrict__ outN,
    int node0, int tid, char* smem) {
    float (*sXT)[D] = (float(*)[D])smem;             // 16 KB
    float (*sWr)[D] = (float(*)[D])(smem + 16384);   // 16 KB
    float (*sWn)[D] = (float(*)[D])(smem + 32768);   // 16 KB

#pragma unroll
    for (int i = 0; i < 4; i++) {
        int idx = tid + 256 * i;
        ((float4*)sWr)[idx] = ((const float4*)Wr)[idx];
        ((float4*)sWn)[idx] = ((const float4*)Wn)[idx];
    }
    int nd = tid & 63;
    int gn = min(node0 + nd, N_NODES - 1);
    if (XBF) {
#pragma unroll
        for (int pass = 0; pass < 2; pass++) {
            int kg = (tid >> 6) + pass * 4;       // 0..7
            int k0 = kg * 8;
            uint4 ux = *(const uint4*)(Xb + (size_t)gn * D + k0);
            sXT[k0 + 0][nd] = bflo(ux.x); sXT[k0 + 1][nd] = bfhi(ux.x);
            sXT[k0 + 2][nd] = bflo(ux.y); sXT[k0 + 3][nd] = bfhi(ux.y);
            sXT[k0 + 4][nd] = bflo(ux.z); sXT[k0 + 5][nd] = bfhi(ux.z);
            sXT[k0 + 6][nd] = bflo(ux.w); sXT[k0 + 7][nd] = bfhi(ux.w);
        }
    } else {
        const float4* X4 = (const float4*)Xf;
#pragma unroll
        for (int pass = 0; pass < 4; pass++) {
            int kq = (tid >> 6) + pass * 4;
            float4 v = X4[gn * 16 + kq];
            sXT[kq * 4 + 0][nd] = v.x; sXT[kq * 4 + 1][nd] = v.y;
            sXT[kq * 4 + 2][nd] = v.z; sXT[kq * 4 + 3][nd] = v.w;
        }
    }
    __syncthreads();

    int nq = tid >> 4;
    int cq = tid & 15;
    float accR[4][4];
    float accN[4][4];
#pragma unroll
    for (int i = 0; i < 4; i++)
#pragma unroll
        for (int jj = 0; jj < 4; jj++) { accR[i][jj] = 0.f; accN[i][jj] = 0.f; }

#pragma unroll 16
    for (int k = 0; k < D; k++) {
        float4 xv = *(const float4*)&sXT[k][nq * 4];
        float4 wr = *(const float4*)&sWr[k][cq * 4];
        float4 wn = *(const float4*)&sWn[k][cq * 4];
        float xs[4] = {xv.x, xv.y, xv.z, xv.w};
        float rs[4] = {wr.x, wr.y, wr.z, wr.w};
        float ns[4] = {wn.x, wn.y, wn.z, wn.w};
#pragma unroll
        for (int i = 0; i < 4; i++)
#pragma unroll
            for (int jj = 0; jj < 4; jj++) {
                accR[i][jj] = fmaf(xs[i], rs[jj], accR[i][jj]);
                accN[i][jj] = fmaf(xs[i], ns[jj], accN[i][jj]);
            }
    }

    float4* outR4 = (float4*)outR;
#pragma unroll
    for (int i = 0; i < 4; i++) {
        int node = node0 + nq * 4 + i;
        if (node < N_NODES) {
            float4 r;
            r.x = accR[i][0]; r.y = accR[i][1];
            r.z = accR[i][2]; r.w = accR[i][3];
            outR4[node * 16 + cq] = r;
            ushort4 rb;
            rb.x = f2bf(accN[i][0]); rb.y = f2bf(accN[i][1]);
            rb.z = f2bf(accN[i][2]); rb.w = f2bf(accN[i][3]);
            *(ushort4*)(outN + (size_t)node * D + cq * 4) = rb;
        }
    }
}

// ---------- merged scatter + layer-1 GEMM (block-specialized) ---------------
__global__ void __launch_bounds__(256) scatter_gemm1(
    const int* __restrict__ src, const int* __restrict__ dst,
    int* __restrict__ cursorPad, int* __restrict__ staged,
    const float* __restrict__ X,
    const float* __restrict__ Wr, const float* __restrict__ Wn,
    float* __restrict__ xr, unsigned short* __restrict__ xn) {
    __shared__ char smem[49152];
    if (blockIdx.x < SBLOCKS) {
        scatter_body(src, dst, cursorPad, staged, smem, blockIdx.x, threadIdx.x);
    } else {
        gemm_body<0>(X, (const unsigned short*)0, Wr, Wn, xr, xn,
                     (blockIdx.x - SBLOCKS) * 64, threadIdx.x, smem);
    }
}

// ---------- standalone layer-2 GEMM (bf16 input) ----------------------------
__global__ void __launch_bounds__(256) gemm2(
    const unsigned short* __restrict__ Xb,
    const float* __restrict__ Wr, const float* __restrict__ Wn,
    float* __restrict__ hr, unsigned short* __restrict__ hn) {
    __shared__ char smem[49152];
    gemm_body<1>((const float*)0, Xb, Wr, Wn, hr, hn,
                 blockIdx.x * 64, threadIdx.x, smem);
}

// ---------- Per-bucket CSR build (LDS-staged csr image, coalesced flush) ----
__global__ void __launch_bounds__(256) csr_build_kernel(
    const int* __restrict__ cursorPad, const int* __restrict__ staged,
    int* __restrict__ csr, int* __restrict__ startA, int* __restrict__ endA) {
    __shared__ int deg[256];
    __shared__ int sc[256];
    __shared__ int curs[256];
    __shared__ int lcsr[BCAP];     // 32 KB staging image
    int k = blockIdx.x;
    int t = threadIdx.x;
    int base = k * BCAP;
    int cnt  = cursorPad[k * 16];
    deg[t] = 0;
    __syncthreads();
    for (int i = t; i < cnt; i += 256)
        atomicAdd(&deg[staged[base + i] & 255], 1);
    __syncthreads();
    int v = deg[t];
    sc[t] = v;
    __syncthreads();
#pragma unroll
    for (int d = 1; d < 256; d <<= 1) {
        int u = (t >= d) ? sc[t - d] : 0;
        __syncthreads();
        sc[t] += u;
        __syncthreads();
    }
    int start = sc[t] - v;
    int node = k * 256 + t;
    if (node < N_NODES) {
        startA[node] = base + start;
        endA[node]   = base + start + v;
    }
    curs[t] = start;
    __syncthreads();
    for (int i = t; i < cnt; i += 256) {
        int e = staged[base + i];
        int pos = atomicAdd(&curs[e & 255], 1);
        lcsr[pos] = e >> 8;                    // LDS scatter (fast)
    }
    __syncthreads();
    for (int i = t; i < cnt; i += 256)         // coalesced flush
        csr[base + i] = lcsr[i];
}

// ---------- Gather (uint4 / 8-lane-row-group) + fused epilogue --------------
// agg = sum of bf16 rows Gsrc[csr[...]]; out = act(Root + agg + bias).
// 8 subs x 8 lanes; each lane loads 16B (8 bf16 dims). Main loop: 16 edges
// per iteration with 2 uint4 loads/lane (half the load instrs of the uint2
// form). Reduce across subs via xor masks 8,16,32.
template<int RELU, int OUTBF>
__global__ void __launch_bounds__(256) gather_fused(
    const unsigned short* __restrict__ Gsrc, const float* __restrict__ Root,
    const float* __restrict__ bias,
    const int* __restrict__ startA, const int* __restrict__ endA,
    const int* __restrict__ csr,
    float* __restrict__ outF, unsigned short* __restrict__ outB) {
    int tid = threadIdx.x;
    int wave = tid >> 6, lane = tid & 63;
    int node = blockIdx.x * 4 + wave;
    int sub = lane >> 3, fq = lane & 7;
    int j0 = startA[node], je = endA[node];
    float a0=0.f,a1=0.f,a2=0.f,a3=0.f,a4=0.f,a5=0.f,a6=0.f,a7=0.f;
    for (int jb = j0; jb < je; jb += 64) {          // je wave-uniform
        int idx = jb + lane;
        int p = csr[idx < je ? idx : (je - 1)];     // coalesced index batch
        int m = min(64, je - jb);                   // wave-uniform
        int b = 0;
        for (; b + 16 <= m; b += 16) {
            int i0 = __shfl(p, b + sub, 64);
            int i1 = __shfl(p, b + 8 + sub, 64);
            uint4 u0 = *(const uint4*)(Gsrc + i0 * D + fq * 8);
            uint4 u1 = *(const uint4*)(Gsrc + i1 * D + fq * 8);
            a0 += bflo(u0.x) + bflo(u1.x);  a1 += bfhi(u0.x) + bfhi(u1.x);
            a2 += bflo(u0.y) + bflo(u1.y);  a3 += bfhi(u0.y) + bfhi(u1.y);
            a4 += bflo(u0.z) + bflo(u1.z);  a5 += bfhi(u0.z) + bfhi(u1.z);
            a6 += bflo(u0.w) + bflo(u1.w);  a7 += bfhi(u0.w) + bfhi(u1.w);
        }
        for (; b < m; b += 8) {                     // uniform condition
            int sidx = b + sub;
            int scl = sidx < m ? sidx : (m - 1);    // active source lane
            int i0 = __shfl(p, scl, 64);            // executed by ALL lanes
            if (sidx < m) {                         // divergence only here
                uint4 u = *(const uint4*)(Gsrc + i0 * D + fq * 8);
                a0 += bflo(u.x); a1 += bfhi(u.x);
                a2 += bflo(u.y); a3 += bfhi(u.y);
                a4 += bflo(u.z); a5 += bfhi(u.z);
                a6 += bflo(u.w); a7 += bfhi(u.w);
            }
        }
    }
#pragma unroll
    for (int mk = 8; mk <= 32; mk <<= 1) {
        a0 += __shfl_xor(a0, mk, 64); a1 += __shfl_xor(a1, mk, 64);
        a2 += __shfl_xor(a2, mk, 64); a3 += __shfl_xor(a3, mk, 64);
        a4 += __shfl_xor(a4, mk, 64); a5 += __shfl_xor(a5, mk, 64);
        a6 += __shfl_xor(a6, mk, 64); a7 += __shfl_xor(a7, mk, 64);
    }
    if (sub == 0) {
        const float* rp = Root + (size_t)node * D + fq * 8;
        float4 x0 = *(const float4*)rp;
        float4 x1 = *(const float4*)(rp + 4);
        float4 b0 = ((const float4*)bias)[fq * 2];
        float4 b1 = ((const float4*)bias)[fq * 2 + 1];
        float r0 = a0 + x0.x + b0.x, r1 = a1 + x0.y + b0.y;
        float r2 = a2 + x0.z + b0.z, r3 = a3 + x0.w + b0.w;
        float r4 = a4 + x1.x + b1.x, r5 = a5 + x1.y + b1.y;
        float r6 = a6 + x1.z + b1.z, r7 = a7 + x1.w + b1.w;
        if (RELU) {
            r0 = fmaxf(r0, 0.f); r1 = fmaxf(r1, 0.f);
            r2 = fmaxf(r2, 0.f); r3 = fmaxf(r3, 0.f);
            r4 = fmaxf(r4, 0.f); r5 = fmaxf(r5, 0.f);
            r6 = fmaxf(r6, 0.f); r7 = fmaxf(r7, 0.f);
        }
        if (OUTBF) {
            uint4 u;
            u.x = (unsigned)f2bf(r0) | ((unsigned)f2bf(r1) << 16);
            u.y = (unsigned)f2bf(r2) | ((unsigned)f2bf(r3) << 16);
            u.z = (unsigned)f2bf(r4) | ((unsigned)f2bf(r5) << 16);
            u.w = (unsigned)f2bf(r6) | ((unsigned)f2bf(r7) << 16);
            *(uint4*)(outB + (size_t)node * D + fq * 8) = u;
        } else {
            float4 w0; w0.x = r0; w0.y = r1; w0.z = r2; w0.w = r3;
            float4 w1; w1.x = r4; w1.y = r5; w1.z = r6; w1.w = r7;
            *(float4*)(outF + (size_t)node * D + fq * 8) = w0;
            *(float4*)(outF + (size_t)node * D + fq * 8 + 4) = w1;
        }
    }
}

// ---------- launch ----------------------------------------------------------
extern "C" void kernel_launch(void* const* d_in, const int* in_sizes, int n_in,
                              void* d_out, int out_size, void* d_ws, size_t ws_size,
                              hipStream_t stream) {
    const float* x   = (const float*)d_in[0];
    const int*   edg = (const int*)d_in[1];
    const float* W1r = (const float*)d_in[2];
    const float* W1n = (const float*)d_in[3];
    const float* b1  = (const float*)d_in[4];
    const float* W2r = (const float*)d_in[5];
    const float* W2n = (const float*)d_in[6];
    const float* b2  = (const float*)d_in[7];
    float* out = (float*)d_out;

    const int* src = edg;
    const int* dst = edg + N_EDGES;

    // ws (256 MiB) — non-overlapping padded layout.
    int* W              = (int*)d_ws;
    int* cursorPad      = W;                         // 196*16 ints
    int* staged         = W + 4096;                  // NBUCKETS*BCAP
    int* csr            = staged + NBUCKETS * BCAP;  // NBUCKETS*BCAP
    int* startA         = csr + NBUCKETS * BCAP;
    int* endA           = startA + N_NODES;
    float* xr           = (float*)(endA + N_NODES);  // fp32 [N][64] root L1
    unsigned short* xn  = (unsigned short*)(xr + (size_t)N_NODES * D); // bf16 x@W1n
    unsigned short* hbf = xn + (size_t)N_NODES * D;  // bf16 h
    float* hr           = (float*)(hbf + (size_t)N_NODES * D);        // fp32 h@W2r
    unsigned short* hn  = (unsigned short*)(hr + (size_t)N_NODES * D); // bf16 h@W2n

    hipMemsetAsync(cursorPad, 0, 196 * 16 * sizeof(int), stream);

    // [scatter || layer-1 dual GEMM]  (xr = x@W1r fp32, xn = x@W1n bf16)
    scatter_gemm1<<<SBLOCKS + MB, 256, 0, stream>>>(
        src, dst, cursorPad, staged, x, W1r, W1n, xr, xn);

    csr_build_kernel<<<NBUCKETS, 256, 0, stream>>>(cursorPad, staged, csr,
                                                   startA, endA);

    const int GB = N_NODES / 4;          // 12500

    // h = relu(xr + segsum(xn[src]) + b1), written bf16.
    gather_fused<1, 1><<<GB, 256, 0, stream>>>(
        xn, xr, b1, startA, endA, csr, (float*)0, hbf);

    // layer-2 dual GEMM: hr = h@W2r fp32, hn = h@W2n bf16.
    gemm2<<<MB, 256, 0, stream>>>(hbf, W2r, W2n, hr, hn);

    // out = hr + segsum(hn[src]) + b2, written fp32.
    gather_fused<0, 0><<<GB, 256, 0, stream>>>(
        hn, hr, b2, startA, endA, csr, out, (unsigned short*)0);
}